// Round 1
// baseline (5386.038 us; speedup 1.0000x reference)
//
#include <hip/hip_runtime.h>

#define NB 8
#define C0 128
#define C1 256
#define NE 16384
#define NEG 0.01f
#define BNEPS 1e-5f

// ---------------- W padding: [O][C][7] -> [O][C][8] (k7 = 0) ----------------
__global__ void pad_w(const float* __restrict__ src, float* __restrict__ dst, int n) {
    int gid = blockIdx.x * blockDim.x + threadIdx.x;
    if (gid < n) {
        const float* s = src + (size_t)gid * 7;
        float4 lo = make_float4(s[0], s[1], s[2], s[3]);
        float4 hi = make_float4(s[4], s[5], s[6], 0.0f);
        float4* d = (float4*)(dst + (size_t)gid * 8);
        d[0] = lo; d[1] = hi;
    }
}

// ---------------- transpose x: [B][C0][E] -> [B][E][C0] ----------------
__global__ void transpose_x(const float* __restrict__ in, float* __restrict__ outp) {
    __shared__ float tile[32][33];
    int b = blockIdx.z;
    int c0 = blockIdx.y * 32;
    int e0 = blockIdx.x * 32;
    int tx = threadIdx.x, ty = threadIdx.y;
#pragma unroll
    for (int i = 0; i < 4; i++) {
        int c = c0 + ty + i * 8;
        tile[ty + i * 8][tx] = in[(size_t)(b * C0 + c) * NE + e0 + tx];
    }
    __syncthreads();
#pragma unroll
    for (int i = 0; i < 4; i++) {
        int e = e0 + ty + i * 8;
        outp[(size_t)(b * NE + e) * C0 + c0 + tx] = tile[tx][ty + i * 8];
    }
}

// ---------------- BN stats over a = leaky(h): per-channel scale/shift ----------------
__global__ void bn_stats(const float* __restrict__ h, const float* __restrict__ gamma,
                         const float* __restrict__ beta, float* __restrict__ st) {
    int o = blockIdx.x;
    int tid = threadIdx.x;
    float sum = 0.f, sq = 0.f;
    for (int b = 0; b < NB; b++) {
        const float4* row = (const float4*)(h + (size_t)(b * C1 + o) * NE);
        for (int i = tid; i < NE / 4; i += 256) {
            float4 v = row[i];
            float a;
            a = v.x >= 0.f ? v.x : NEG * v.x; sum += a; sq += a * a;
            a = v.y >= 0.f ? v.y : NEG * v.y; sum += a; sq += a * a;
            a = v.z >= 0.f ? v.z : NEG * v.z; sum += a; sq += a * a;
            a = v.w >= 0.f ? v.w : NEG * v.w; sum += a; sq += a * a;
        }
    }
    __shared__ float rs[256], rq[256];
    rs[tid] = sum; rq[tid] = sq;
    __syncthreads();
    for (int s = 128; s > 0; s >>= 1) {
        if (tid < s) { rs[tid] += rs[tid + s]; rq[tid] += rq[tid + s]; }
        __syncthreads();
    }
    if (tid == 0) {
        float n = (float)NB * (float)NE;
        float mean = rs[0] / n;
        float var = rq[0] / n - mean * mean;
        float sc = gamma[o] * rsqrtf(var + BNEPS);
        st[o] = sc;
        st[C1 + o] = beta[o] - mean * sc;
    }
}

// ---------------- BN apply + leaky + transpose: h[B][C1][E] -> a_t[B][E][C1] ----------------
__global__ void bn_transpose(const float* __restrict__ h, const float* __restrict__ st,
                             float* __restrict__ outp) {
    __shared__ float tile[32][33];
    int b = blockIdx.z;
    int c0 = blockIdx.y * 32;
    int e0 = blockIdx.x * 32;
    int tx = threadIdx.x, ty = threadIdx.y;
#pragma unroll
    for (int i = 0; i < 4; i++) {
        int c = c0 + ty + i * 8;
        float v = h[(size_t)(b * C1 + c) * NE + e0 + tx];
        float a = v >= 0.f ? v : NEG * v;
        tile[ty + i * 8][tx] = a * st[c] + st[C1 + c];
    }
    __syncthreads();
#pragma unroll
    for (int i = 0; i < 4; i++) {
        int e = e0 + ty + i * 8;
        outp[(size_t)(b * NE + e) * C1 + c0 + tx] = tile[tx][ty + i * 8];
    }
}

// ---------------- 7 symmetric features ----------------
__device__ inline void feat7(float a0, float a1, float a2, float a3, float a4, float* g) {
    float s13 = a1 + a3, s24 = a2 + a4;
    float d13 = fabsf(a1 - a3), d24 = fabsf(a2 - a4);
    float s = s13 + s24;
    float avg = 0.25f * s;
    float q1 = a1 - avg, q2 = a2 - avg, q3 = a3 - avg, q4 = a4 - avg;
    float v6 = q1 * q1 + q2 * q2 + q3 * q3 + q4 * q4;
    float4* gv = (float4*)g;
    gv[0] = make_float4(a0, s13, s24, d13);
    gv[1] = make_float4(d24, s, v6, 0.0f);
}

// ---------------- conv0: out h0[b][o][e] = sum_{c,k} G(x)[b,c,e,k] W0[o,c,k] ----------------
// block: 256 threads = one o each; e-tile 16; LDS G tile [16][128][8] f32 = 64 KB
__global__ __launch_bounds__(256) void conv0_kernel(const float* __restrict__ xt,
                                                    const int* __restrict__ gidx,
                                                    const float* __restrict__ Wp,
                                                    float* __restrict__ h0) {
    __shared__ float G[16 * C0 * 8];
    int b = blockIdx.y;
    int e0 = blockIdx.x * 16;
    int tid = threadIdx.x;

    const float4* xb = (const float4*)xt;
#pragma unroll
    for (int it = 0; it < 2; it++) {
        int task = tid + it * 256;      // 512 tasks: 16 e x 32 c4
        int e = task >> 5;
        int c4 = task & 31;
        int4 gi = *(const int4*)(gidx + (size_t)(b * NE + e0 + e) * 4);
        int rb = b * NE;
        float4 f0 = xb[(size_t)(rb + e0 + e) * (C0 / 4) + c4];
        float4 f1 = xb[(size_t)(rb + gi.x) * (C0 / 4) + c4];
        float4 f2 = xb[(size_t)(rb + gi.y) * (C0 / 4) + c4];
        float4 f3 = xb[(size_t)(rb + gi.z) * (C0 / 4) + c4];
        float4 f4 = xb[(size_t)(rb + gi.w) * (C0 / 4) + c4];
        const float* p0 = (const float*)&f0;
        const float* p1 = (const float*)&f1;
        const float* p2 = (const float*)&f2;
        const float* p3 = (const float*)&f3;
        const float* p4 = (const float*)&f4;
#pragma unroll
        for (int ci = 0; ci < 4; ci++) {
            int c = c4 * 4 + ci;
            feat7(p0[ci], p1[ci], p2[ci], p3[ci], p4[ci], &G[(e * C0 + c) * 8]);
        }
    }
    __syncthreads();

    float acc[16];
#pragma unroll
    for (int e = 0; e < 16; e++) acc[e] = 0.f;
    const float4* Wv = (const float4*)(Wp + (size_t)tid * C0 * 8);
    const float4* Gv = (const float4*)G;
    for (int c = 0; c < C0; c++) {
        float4 wlo = Wv[c * 2], whi = Wv[c * 2 + 1];
#pragma unroll
        for (int e = 0; e < 16; e++) {
            float4 glo = Gv[(e * C0 + c) * 2];
            float4 ghi = Gv[(e * C0 + c) * 2 + 1];
            acc[e] += glo.x * wlo.x + glo.y * wlo.y + glo.z * wlo.z + glo.w * wlo.w
                    + ghi.x * whi.x + ghi.y * whi.y + ghi.z * whi.z;
        }
    }
    float* orow = h0 + (size_t)(b * C1 + tid) * NE + e0;
#pragma unroll
    for (int e = 0; e < 16; e++) orow[e] = acc[e];
}

// ---------------- conv1 + residual + leaky ----------------
// block: 256 threads = one o each; e-tile 16; c in 2 chunks of 128; LDS 64 KB
__global__ __launch_bounds__(256) void conv1_kernel(const float* __restrict__ at,
                                                    const int* __restrict__ gidx,
                                                    const float* __restrict__ Wp,
                                                    const float* __restrict__ x1,
                                                    float* __restrict__ outp) {
    __shared__ float G[16 * 128 * 8];
    int b = blockIdx.y;
    int e0 = blockIdx.x * 16;
    int tid = threadIdx.x;

    float acc[16];
#pragma unroll
    for (int e = 0; e < 16; e++) acc[e] = 0.f;

    const float4* xb = (const float4*)at;
    const float4* Wv = (const float4*)(Wp + (size_t)tid * C1 * 8);
    const float4* Gv = (const float4*)G;

    for (int chunk = 0; chunk < 2; chunk++) {
        __syncthreads();
#pragma unroll
        for (int it = 0; it < 2; it++) {
            int task = tid + it * 256;   // 512 tasks: 16 e x 32 c4 (within chunk)
            int e = task >> 5;
            int c4 = task & 31;
            int cg4 = chunk * 32 + c4;
            int4 gi = *(const int4*)(gidx + (size_t)(b * NE + e0 + e) * 4);
            int rb = b * NE;
            float4 f0 = xb[(size_t)(rb + e0 + e) * (C1 / 4) + cg4];
            float4 f1 = xb[(size_t)(rb + gi.x) * (C1 / 4) + cg4];
            float4 f2 = xb[(size_t)(rb + gi.y) * (C1 / 4) + cg4];
            float4 f3 = xb[(size_t)(rb + gi.z) * (C1 / 4) + cg4];
            float4 f4 = xb[(size_t)(rb + gi.w) * (C1 / 4) + cg4];
            const float* p0 = (const float*)&f0;
            const float* p1 = (const float*)&f1;
            const float* p2 = (const float*)&f2;
            const float* p3 = (const float*)&f3;
            const float* p4 = (const float*)&f4;
#pragma unroll
            for (int ci = 0; ci < 4; ci++) {
                int c = c4 * 4 + ci;
                feat7(p0[ci], p1[ci], p2[ci], p3[ci], p4[ci], &G[(e * 128 + c) * 8]);
            }
        }
        __syncthreads();

        for (int c = 0; c < 128; c++) {
            int cg = chunk * 128 + c;
            float4 wlo = Wv[cg * 2], whi = Wv[cg * 2 + 1];
#pragma unroll
            for (int e = 0; e < 16; e++) {
                float4 glo = Gv[(e * 128 + c) * 2];
                float4 ghi = Gv[(e * 128 + c) * 2 + 1];
                acc[e] += glo.x * wlo.x + glo.y * wlo.y + glo.z * wlo.z + glo.w * wlo.w
                        + ghi.x * whi.x + ghi.y * whi.y + ghi.z * whi.z;
            }
        }
    }

    const float* xr = x1 + (size_t)(b * C1 + tid) * NE + e0;
    float* orow = outp + (size_t)(b * C1 + tid) * NE + e0;
#pragma unroll
    for (int e = 0; e < 16; e++) {
        float v = acc[e] + xr[e];
        orow[e] = v >= 0.f ? v : NEG * v;
    }
}

// ---------------- host ----------------
extern "C" void kernel_launch(void* const* d_in, const int* in_sizes, int n_in,
                              void* d_out, int out_size, void* d_ws, size_t ws_size,
                              hipStream_t stream) {
    const float* x     = (const float*)d_in[0];   // [8][128][16384]
    const int*   gemm  = (const int*)d_in[1];     // [8][16384][4]
    const float* W0    = (const float*)d_in[2];   // [256][128][7]
    const float* W1    = (const float*)d_in[3];   // [256][256][7]
    const float* gamma = (const float*)d_in[4];   // [256]
    const float* beta  = (const float*)d_in[5];   // [256]
    float* outp = (float*)d_out;                  // [8][256][16384]

    char* ws = (char*)d_ws;
    // region A (128 MB): x_t [B][E][C0] (64 MB) during conv0, then a_t [B][E][C1]
    float* xt  = (float*)ws;
    float* at  = (float*)ws;
    // region B (128 MB): h0 (= residual x1)
    float* h0  = (float*)(ws + (size_t)128 * 1024 * 1024);
    // W pads + stats
    float* W0p = (float*)(ws + (size_t)256 * 1024 * 1024);            // 1 MB
    float* W1p = (float*)(ws + (size_t)257 * 1024 * 1024);            // 2 MB
    float* st  = (float*)(ws + (size_t)259 * 1024 * 1024);            // 2 KB

    pad_w<<<dim3((C1 * C0 + 255) / 256), dim3(256), 0, stream>>>(W0, W0p, C1 * C0);
    pad_w<<<dim3((C1 * C1 + 255) / 256), dim3(256), 0, stream>>>(W1, W1p, C1 * C1);
    transpose_x<<<dim3(NE / 32, C0 / 32, NB), dim3(32, 8), 0, stream>>>(x, xt);
    conv0_kernel<<<dim3(NE / 16, NB), dim3(256), 0, stream>>>(xt, gemm, W0p, h0);
    bn_stats<<<dim3(C1), dim3(256), 0, stream>>>(h0, gamma, beta, st);
    bn_transpose<<<dim3(NE / 32, C1 / 32, NB), dim3(32, 8), 0, stream>>>(h0, st, at);
    conv1_kernel<<<dim3(NE / 16, NB), dim3(256), 0, stream>>>(at, gemm, W1p, h0, outp);
}

// Round 2
// 651.842 us; speedup vs baseline: 8.2628x; 8.2628x over previous
//
#include <hip/hip_runtime.h>
#include <hip/hip_bf16.h>

#define NB 8
#define C1 256
#define NE 16384
#define NEG 0.01f
#define BNEPS 1e-5f

typedef __attribute__((ext_vector_type(4))) float f32x4;
typedef __attribute__((ext_vector_type(8))) short s16x8;
typedef unsigned short ushort;
typedef unsigned int uint;

__device__ __forceinline__ ushort f2b(float f) {
    union { float f; uint u; } v; v.f = f;
    uint u = v.u;
    uint r = u + 0x7fffu + ((u >> 16) & 1u);
    return (ushort)(r >> 16);
}
__device__ __forceinline__ float b2f_lo(uint g) {
    union { uint u; float f; } v; v.u = g << 16; return v.f;
}
__device__ __forceinline__ float b2f_hi(uint g) {
    union { uint u; float f; } v; v.u = g & 0xffff0000u; return v.f;
}

__device__ __forceinline__ void gld_lds16(const void* g, void* l) {
    __builtin_amdgcn_global_load_lds(
        (const __attribute__((address_space(1))) unsigned int*)g,
        (__attribute__((address_space(3))) unsigned int*)l,
        16, 0, 0);
}

// ---- W prep: [256][CIN][7] f32 -> [256][CIN*8] bf16, k7=0, slot-swizzled ----
// physical slot p (16B octet) within each 64k chunk holds logical slot p^(o&7)
template<int CIN>
__global__ void pad_w_sw(const float* __restrict__ W, ushort* __restrict__ Wsw) {
    int gid = blockIdx.x * blockDim.x + threadIdx.x;
    if (gid >= 256 * CIN) return;
    int o = gid / CIN, c = gid % CIN;
    int chunk = c >> 3, s = c & 7, sp = s ^ (o & 7);
    const float* src = W + (size_t)gid * 7;
    ushort* dst = Wsw + ((size_t)o * CIN + chunk * 8 + sp) * 8;
#pragma unroll
    for (int j = 0; j < 7; j++) dst[j] = f2b(src[j]);
    dst[7] = 0;
}

// ---- transpose x: [B][128][E] f32 -> xt [B][E][128] bf16 ----
__global__ void transpose_x_bf16(const float* __restrict__ in, ushort* __restrict__ outp) {
    __shared__ float tile[32][33];
    int b = blockIdx.z, c0 = blockIdx.y * 32, e0 = blockIdx.x * 32;
    int tx = threadIdx.x, ty = threadIdx.y;
#pragma unroll
    for (int i = 0; i < 4; i++)
        tile[ty + i * 8][tx] = in[(size_t)(b * 128 + c0 + ty + i * 8) * NE + e0 + tx];
    __syncthreads();
#pragma unroll
    for (int i = 0; i < 4; i++)
        outp[((size_t)b * NE + e0 + ty + i * 8) * 128 + c0 + tx] = f2b(tile[tx][ty + i * 8]);
}

// ---- BN stats over a = leaky(h): per-channel scale/shift ----
__global__ void bn_stats(const float* __restrict__ h, const float* __restrict__ gamma,
                         const float* __restrict__ beta, float* __restrict__ st) {
    int o = blockIdx.x;
    int tid = threadIdx.x;
    float sum = 0.f, sq = 0.f;
    for (int b = 0; b < NB; b++) {
        const float4* row = (const float4*)(h + (size_t)(b * C1 + o) * NE);
        for (int i = tid; i < NE / 4; i += 256) {
            float4 v = row[i];
            float a;
            a = v.x >= 0.f ? v.x : NEG * v.x; sum += a; sq += a * a;
            a = v.y >= 0.f ? v.y : NEG * v.y; sum += a; sq += a * a;
            a = v.z >= 0.f ? v.z : NEG * v.z; sum += a; sq += a * a;
            a = v.w >= 0.f ? v.w : NEG * v.w; sum += a; sq += a * a;
        }
    }
    __shared__ float rs[256], rq[256];
    rs[tid] = sum; rq[tid] = sq;
    __syncthreads();
    for (int s = 128; s > 0; s >>= 1) {
        if (tid < s) { rs[tid] += rs[tid + s]; rq[tid] += rq[tid + s]; }
        __syncthreads();
    }
    if (tid == 0) {
        float n = (float)NB * (float)NE;
        float mean = rs[0] / n;
        float var = rq[0] / n - mean * mean;
        float sc = gamma[o] * rsqrtf(var + BNEPS);
        st[o] = sc;
        st[C1 + o] = beta[o] - mean * sc;
    }
}

// ---- BN apply + leaky + transpose: h[B][256][E] f32 -> at [B][E][256] bf16 ----
__global__ void bn_transpose_bf16(const float* __restrict__ h, const float* __restrict__ st,
                                  ushort* __restrict__ outp) {
    __shared__ float tile[32][33];
    int b = blockIdx.z, c0 = blockIdx.y * 32, e0 = blockIdx.x * 32;
    int tx = threadIdx.x, ty = threadIdx.y;
#pragma unroll
    for (int i = 0; i < 4; i++) {
        int c = c0 + ty + i * 8;
        float v = h[(size_t)(b * C1 + c) * NE + e0 + tx];
        float a = v >= 0.f ? v : NEG * v;
        tile[ty + i * 8][tx] = a * st[c] + st[C1 + c];
    }
    __syncthreads();
#pragma unroll
    for (int i = 0; i < 4; i++)
        outp[((size_t)b * NE + e0 + ty + i * 8) * C1 + c0 + tx] = f2b(tile[tx][ty + i * 8]);
}

// ---- fused gather-feature MFMA GEMM ----
// out[b][o][e] = sum_{c,k} G[b,c,e,k] * W[o,c,k]
// BM=256 (all o), BN=128 edges, BK=64 (8 ch x 8 k), 512 threads = 8 waves (4M x 2N)
template<int CIN, bool FUSE>
__global__ __launch_bounds__(512, 1) void mesh_gemm(
    const ushort* __restrict__ at,   // [B][E][CIN] bf16
    const int* __restrict__ gidx,    // [B][E][4]
    const ushort* __restrict__ Wsw,  // [256][CIN*8] bf16 pre-swizzled
    const float* __restrict__ x1,    // residual [B][256][E] (FUSE only)
    float* __restrict__ outp) {      // [B][256][E]
    constexpr int K = CIN * 8;
    constexpr int NSTEP = K / 64;

    __shared__ short Al[2][256 * 64];  // 64 KB
    __shared__ short Bl[2][128 * 64];  // 32 KB

    // XCD-aware swizzle (1024 % 8 == 0)
    int nwg = gridDim.x;
    int wg = (blockIdx.x & 7) * (nwg >> 3) + (blockIdx.x >> 3);
    int b = wg >> 7;
    int e0 = (wg & 127) * 128;

    int tid = threadIdx.x;
    int ln = tid & 63;
    int wv = tid >> 6;
    int wm = wv & 3;        // 4 M-waves
    int wn = wv >> 2;       // 2 N-waves
    int lr = ln & 15;
    int lk = ln >> 4;

    // ---- gather setup (fixed per thread across K-steps) ----
    int ge = tid >> 2;      // edge within tile 0..127
    int gq = tid & 3;       // channel-pair 0..3
    const int4 gi = *(const int4*)(gidx + ((size_t)b * NE + e0 + ge) * 4);
    const ushort* abase = at + (size_t)b * NE * CIN;
    const ushort* p0 = abase + (size_t)(e0 + ge) * CIN + gq * 2;
    const ushort* p1 = abase + (size_t)gi.x * CIN + gq * 2;
    const ushort* p2 = abase + (size_t)gi.y * CIN + gq * 2;
    const ushort* p3 = abase + (size_t)gi.z * CIN + gq * 2;
    const ushort* p4 = abase + (size_t)gi.w * CIN + gq * 2;

    // ---- A staging setup ----
    int srow = tid >> 3;    // 0..63
    int sslot = tid & 7;
    const ushort* wbase = Wsw + (size_t)srow * K + sslot * 8;
    int ldsbase = wv * 1024;  // byte, + i*8192, uniform per wave

    // ---- frag read offsets ----
    int arb[4], brb[4];
#pragma unroll
    for (int m = 0; m < 4; m++) arb[m] = (wm * 64 + m * 16 + lr) * 128;
#pragma unroll
    for (int n = 0; n < 4; n++) brb[n] = (wn * 64 + n * 16 + lr) * 128;
    int sx0 = ((0 * 4 + lk) ^ (lr & 7)) << 4;  // wm*64 etc ≡ 0 mod 8
    int sx1 = ((1 * 4 + lk) ^ (lr & 7)) << 4;

    f32x4 acc[4][4];
#pragma unroll
    for (int m = 0; m < 4; m++)
#pragma unroll
        for (int n = 0; n < 4; n++) acc[m][n] = (f32x4){0.f, 0.f, 0.f, 0.f};

    // ---- B-gen helper (macro-ish lambda) ----
    auto gen_write = [&](int buf, uint g0, uint g1, uint g2, uint g3, uint g4) {
        char* Bd = (char*)Bl[buf];
#pragma unroll
        for (int j = 0; j < 2; j++) {
            float a0, a1, a2, a3, a4;
            if (j == 0) { a0 = b2f_lo(g0); a1 = b2f_lo(g1); a2 = b2f_lo(g2); a3 = b2f_lo(g3); a4 = b2f_lo(g4); }
            else        { a0 = b2f_hi(g0); a1 = b2f_hi(g1); a2 = b2f_hi(g2); a3 = b2f_hi(g3); a4 = b2f_hi(g4); }
            float s13 = a1 + a3, s24 = a2 + a4;
            float d13 = fabsf(a1 - a3), d24 = fabsf(a2 - a4);
            float s = s13 + s24, avg = 0.25f * s;
            float q1 = a1 - avg, q2 = a2 - avg, q3 = a3 - avg, q4 = a4 - avg;
            float v6 = q1 * q1 + q2 * q2 + q3 * q3 + q4 * q4;
            s16x8 pk;
            pk[0] = (short)f2b(a0);  pk[1] = (short)f2b(s13);
            pk[2] = (short)f2b(s24); pk[3] = (short)f2b(d13);
            pk[4] = (short)f2b(d24); pk[5] = (short)f2b(s);
            pk[6] = (short)f2b(v6);  pk[7] = 0;
            int slot = gq * 2 + j;
            *(s16x8*)(Bd + ge * 128 + ((slot ^ (ge & 7)) << 4)) = pk;
        }
    };
    auto stageA = [&](int buf, int t) {
#pragma unroll
        for (int i = 0; i < 4; i++)
            gld_lds16(wbase + (size_t)i * 64 * K + t * 64,
                      (char*)Al[buf] + ldsbase + i * 8192);
    };

    // ---- prologue: stage step 0 ----
    stageA(0, 0);
    {
        uint g0 = *(const uint*)p0, g1 = *(const uint*)p1, g2 = *(const uint*)p2,
             g3 = *(const uint*)p3, g4 = *(const uint*)p4;
        gen_write(0, g0, g1, g2, g3, g4);
    }
    __syncthreads();

    // ---- main loop ----
    for (int t = 0; t < NSTEP; ++t) {
        int cur = t & 1;
        bool more = (t + 1) < NSTEP;
        uint g0, g1, g2, g3, g4;
        if (more) {
            stageA(cur ^ 1, t + 1);
            int off = (t + 1) * 8;
            g0 = *(const uint*)(p0 + off); g1 = *(const uint*)(p1 + off);
            g2 = *(const uint*)(p2 + off); g3 = *(const uint*)(p3 + off);
            g4 = *(const uint*)(p4 + off);
        }
        const char* Ac = (const char*)Al[cur];
        const char* Bc = (const char*)Bl[cur];
#pragma unroll
        for (int kk = 0; kk < 2; kk++) {
            int sx = kk ? sx1 : sx0;
            s16x8 af[4], bf[4];
#pragma unroll
            for (int m = 0; m < 4; m++) af[m] = *(const s16x8*)(Ac + arb[m] + sx);
#pragma unroll
            for (int n = 0; n < 4; n++) bf[n] = *(const s16x8*)(Bc + brb[n] + sx);
#pragma unroll
            for (int m = 0; m < 4; m++)
#pragma unroll
                for (int n = 0; n < 4; n++)
                    acc[m][n] = __builtin_amdgcn_mfma_f32_16x16x32_bf16(af[m], bf[n], acc[m][n], 0, 0, 0);
        }
        if (more) gen_write(cur ^ 1, g0, g1, g2, g3, g4);
        __syncthreads();
    }

    // ---- epilogue ----
    size_t obase = (size_t)b * 256 * NE + e0;
#pragma unroll
    for (int m = 0; m < 4; m++) {
        int o0 = wm * 64 + m * 16 + lk * 4;
#pragma unroll
        for (int n = 0; n < 4; n++) {
            int el = wn * 64 + n * 16 + lr;
            f32x4 v = acc[m][n];
#pragma unroll
            for (int r = 0; r < 4; r++) {
                size_t idx = obase + (size_t)(o0 + r) * NE + el;
                if (FUSE) {
                    float u = v[r] + x1[idx];
                    outp[idx] = u >= 0.f ? u : NEG * u;
                } else {
                    outp[idx] = v[r];
                }
            }
        }
    }
}

// ---------------- host ----------------
extern "C" void kernel_launch(void* const* d_in, const int* in_sizes, int n_in,
                              void* d_out, int out_size, void* d_ws, size_t ws_size,
                              hipStream_t stream) {
    const float* x     = (const float*)d_in[0];   // [8][128][16384]
    const int*   gemm  = (const int*)d_in[1];     // [8][16384][4]
    const float* W0    = (const float*)d_in[2];   // [256][128][7]
    const float* W1    = (const float*)d_in[3];   // [256][256][7]
    const float* gamma = (const float*)d_in[4];
    const float* beta  = (const float*)d_in[5];
    float* outp = (float*)d_out;                  // [8][256][16384]

    char* ws = (char*)d_ws;
    ushort* xt  = (ushort*)ws;                                   // 32 MB  [B][E][128] bf16
    ushort* at  = (ushort*)ws;                                   // 64 MB  [B][E][256] bf16 (after conv0)
    float*  h0  = (float*)(ws + (size_t)64 * 1024 * 1024);       // 128 MB [B][256][E] f32
    ushort* Wsw0 = (ushort*)(ws + (size_t)192 * 1024 * 1024);    // 512 KB
    ushort* Wsw1 = (ushort*)(ws + (size_t)193 * 1024 * 1024);    // 1 MB
    float*  st   = (float*)(ws + (size_t)195 * 1024 * 1024);     // 2 KB

    pad_w_sw<128><<<dim3((256 * 128 + 255) / 256), dim3(256), 0, stream>>>(W0, Wsw0);
    pad_w_sw<256><<<dim3((256 * 256 + 255) / 256), dim3(256), 0, stream>>>(W1, Wsw1);
    transpose_x_bf16<<<dim3(NE / 32, 128 / 32, NB), dim3(32, 8), 0, stream>>>(x, xt);
    mesh_gemm<128, false><<<dim3(1024), dim3(512), 0, stream>>>(xt, gemm, Wsw0, nullptr, h0);
    bn_stats<<<dim3(C1), dim3(256), 0, stream>>>(h0, gamma, beta, st);
    bn_transpose_bf16<<<dim3(NE / 32, C1 / 32, NB), dim3(32, 8), 0, stream>>>(h0, st, at);
    mesh_gemm<256, true><<<dim3(1024), dim3(512), 0, stream>>>(at, gemm, Wsw1, h0, outp);
}